// Round 19
// baseline (108.692 us; speedup 1.0000x reference)
//
#include <hip/hip_runtime.h>
#include <hip/hip_fp16.h>

#define N_NODES 100000
#define N_EDGES 3200000
#define IN_DIM 6
#define HID_DIM 32
#define LAT_DIM 16

#define NPB 128                      // nodes per bucket (dst >> 7)
#define NB 782                       // ceil(100000 / 128)
#define CAP 4800                     // bucket segment capacity (mean 4092, sigma 64)
#define AB_BLOCKS 800
#define CH (N_EDGES / AB_BLOCKS)     // 4000 edges per place block (exact, even)
#define PL_T 512                     // threads in k_bplace
#define SORT_T 512                   // threads in k_sort
#define LP2_CAP 2560                 // 64-node perm stage (mean 2048, sigma 45)

// ---------------- init bucket cursors to segment bases ----------------
__global__ void k_init(int* __restrict__ bcur) {
    int i = blockIdx.x * blockDim.x + threadIdx.x;
    if (i < NB) bcur[i] = i * CAP;
}

// ---------------- place edges: int2 loads, LDS counting-sort staging -> coalesced writes ----------------
__global__ void __launch_bounds__(PL_T) k_bplace(const int* __restrict__ src,
                                                 const int* __restrict__ dst,
                                                 int* __restrict__ bcur,
                                                 int* __restrict__ bedge, int E) {
    __shared__ int hist[NB];
    __shared__ int lbase[NB];
    __shared__ int gbase[NB];
    __shared__ int cur[NB];
    __shared__ int part[PL_T];
    __shared__ int stage[CH];
    __shared__ unsigned short sbkt[CH];
    int t = threadIdx.x;
    for (int i = t; i < NB; i += PL_T) { hist[i] = 0; cur[i] = 0; }
    __syncthreads();
    int beg = blockIdx.x * CH, end = min(beg + CH, E);
    int nv = (end - beg) >> 1;                       // CH even, beg*4 8B-aligned
    const int2* dst2 = (const int2*)(dst + beg);
    const long long* src2 = (const long long*)(src + beg);  // nt-legal scalar type
    // pass 1: histogram (regular dst loads -- slice re-read in pass 2, L1-hot)
    for (int i = t; i < nv; i += PL_T) {
        int2 d = dst2[i];
        atomicAdd(&hist[d.x >> 7], 1);
        atomicAdd(&hist[d.y >> 7], 1);
    }
    if (((end - beg) & 1) && t == 0) atomicAdd(&hist[dst[end - 1] >> 7], 1);
    __syncthreads();
    // exclusive scan of hist -> lbase (2 elems/thread)
    int i0 = 2 * t;
    int a = (i0 < NB) ? hist[i0] : 0;
    int b = (i0 + 1 < NB) ? hist[i0 + 1] : 0;
    part[t] = a + b;
    __syncthreads();
    for (int off = 1; off < PL_T; off <<= 1) {
        int v = (t >= off) ? part[t - off] : 0;
        __syncthreads();
        part[t] += v;
        __syncthreads();
    }
    int ex = (t == 0) ? 0 : part[t - 1];
    if (i0 < NB) lbase[i0] = ex;
    if (i0 + 1 < NB) lbase[i0 + 1] = ex + a;
    __syncthreads();
    // reserve global ranges per bucket (bcur pre-seeded to b*CAP)
    for (int i = t; i < NB; i += PL_T)
        gbase[i] = hist[i] ? atomicAdd(&bcur[i], hist[i]) : 0;
    __syncthreads();
    // pass 2: scatter into LDS staging, sorted by bucket (dst L1-hot; src read-once nt)
    for (int i = t; i < nv; i += PL_T) {
        int2 d = dst2[i];
        long long sv = __builtin_nontemporal_load(src2 + i);
        int s0 = (int)(sv & 0xFFFFFFFFLL);
        int s1 = (int)(sv >> 32);
        int bkt0 = d.x >> 7;
        int r0 = atomicAdd(&cur[bkt0], 1);
        int pos0 = lbase[bkt0] + r0;
        stage[pos0] = (s0 << 7) | (d.x & (NPB - 1));
        sbkt[pos0] = (unsigned short)bkt0;
        int bkt1 = d.y >> 7;
        int r1 = atomicAdd(&cur[bkt1], 1);
        int pos1 = lbase[bkt1] + r1;
        stage[pos1] = (s1 << 7) | (d.y & (NPB - 1));
        sbkt[pos1] = (unsigned short)bkt1;
    }
    if (((end - beg) & 1) && t == 0) {
        int d = dst[end - 1], s = src[end - 1];
        int bkt = d >> 7;
        int r = atomicAdd(&cur[bkt], 1);
        int pos = lbase[bkt] + r;
        stage[pos] = (s << 7) | (d & (NPB - 1));
        sbkt[pos] = (unsigned short)bkt;
    }
    __syncthreads();
    // stream out: coalesced within bucket runs; regular store (k_sort re-reads via L2/L3)
    int total = end - beg;
    for (int j = t; j < total; j += PL_T) {
        int bkt = sbkt[j];
        bedge[gbase[bkt] + (j - lbase[bkt])] = stage[j];
    }
}

// ---------------- per-bucket counting sort, SINGLE global pass over bedge ----------------
__global__ void __launch_bounds__(SORT_T) k_sort(const int* __restrict__ bcur,
                                                 const int* __restrict__ bedge,
                                                 const float* __restrict__ x,
                                                 int2* __restrict__ rowse,
                                                 int* __restrict__ perm,
                                                 float* __restrict__ dinv,
                                                 __half* __restrict__ xs, int N) {
    int b = blockIdx.x;
    __shared__ int cnt[NPB], base[NPB], cur[NPB], scn[NPB];
    __shared__ float dvs[NPB];
    __shared__ int raw[CAP];   // 19.2 KB
    __shared__ int srt[CAP];   // 19.2 KB
    int t = threadIdx.x;
    if (t < NPB) cnt[t] = 0;
    __syncthreads();
    int beg = b * CAP, end = bcur[b];
    int m = end - beg;
    // single global read: stash word + histogram in one pass
    for (int k = t; k < m; k += SORT_T) {
        int w = bedge[beg + k];
        raw[k] = w;
        atomicAdd(&cnt[w & (NPB - 1)], 1);
    }
    __syncthreads();
    if (t < NPB) scn[t] = cnt[t];
    __syncthreads();
    for (int off = 1; off < NPB; off <<= 1) {
        int v = 0;
        if (t < NPB && t >= off) v = scn[t - off];
        __syncthreads();
        if (t < NPB) scn[t] += v;
        __syncthreads();
    }
    if (t < NPB) {
        int ex = scn[t] - cnt[t];  // exclusive
        base[t] = ex;
        cur[t] = 0;
        int node = (b << 7) + t;
        if (node < N) {
            float dv = rsqrtf((float)(cnt[t] + 1));  // +1 self-loop
            dvs[t] = dv;
            dinv[node] = dv;
            rowse[node] = make_int2(beg + ex, beg + ex + cnt[t]);
        }
    }
    __syncthreads();
    // LDS -> LDS scatter (no global traffic)
    for (int k = t; k < m; k += SORT_T) {
        int w = raw[k];
        int dl = w & (NPB - 1);
        int pos = base[dl] + atomicAdd(&cur[dl], 1);
        srt[pos] = w >> 7;
    }
    __syncthreads();
    // coalesced stream-out; regular store (perm read twice downstream)
    for (int k = t; k < m; k += SORT_T)
        perm[beg + k] = srt[k];
    // fused: xs[n][d] = fp16(x[n][d] * dinv[n]), padded to 8 halfs (16B rows)
    for (int i = t; i < NPB * 4; i += SORT_T) {
        int nl = i >> 2, d2 = (i & 3) * 2;
        int node = (b << 7) + nl;
        if (node < N) {
            float dv = dvs[nl];
            float v0 = (d2 < IN_DIM) ? x[(size_t)node * IN_DIM + d2] * dv : 0.f;
            float v1 = (d2 + 1 < IN_DIM) ? x[(size_t)node * IN_DIM + d2 + 1] * dv : 0.f;
            *(__half2*)(xs + (size_t)node * 8 + d2) = __floats2half2_rn(v0, v1);
        }
    }
}

// ---------------- layer 1 fused: 64 nodes/block, 4 lanes/node, half2 MLP-16 gather
//                  -> W1+relu -> W2 -> h2s (fp16) ----------------
__global__ void __launch_bounds__(256) k_agg1f(const int2* __restrict__ rowse,
                                               const int* __restrict__ perm,
                                               const __half* __restrict__ xs,
                                               const float* __restrict__ dinv,
                                               const float* __restrict__ b1,
                                               const float* __restrict__ W1,
                                               const float* __restrict__ W2,
                                               __half* __restrict__ h2s, int N) {
    __shared__ float w1[IN_DIM * HID_DIM];
    __shared__ float w2[HID_DIM * LAT_DIM];
    __shared__ float bsh[HID_DIM];
    __shared__ float ash[64][HID_DIM + 1];
    __shared__ float y[64][9];       // pad 9: avoid 4-way conflict on row reads
    __shared__ int lperm[LP2_CAP];
    int t = threadIdx.x;
    for (int i = t; i < IN_DIM * HID_DIM; i += 256) w1[i] = W1[i];
    for (int i = t; i < HID_DIM * LAT_DIM; i += 256) w2[i] = W2[i];
    if (t < HID_DIM) bsh[t] = b1[t];
    int nl = t >> 2, p = t & 3;
    int n0 = blockIdx.x * 64;
    int node = n0 + nl;
    int nlast = min(n0 + 63, N - 1);   // 64-group never crosses a bucket (64 | 128)
    int gbeg = rowse[n0].x;
    int gend = rowse[nlast].y;
    int m = gend - gbeg;
    bool valid = (node <= nlast);
    int2 se = valid ? rowse[node] : make_int2(gbeg, gbeg);
    float2 acc = make_float2(0.f, 0.f);
    if (m <= LP2_CAP) {
        for (int i = t; i < m; i += 256) lperm[i] = perm[gbeg + i];  // regular: L2/L3 hit
        __syncthreads();
        int k = se.x - gbeg, lend = se.y - gbeg;
        for (; k + 16 <= lend; k += 16) {
            int ss[16];
#pragma unroll
            for (int j = 0; j < 16; j++) ss[j] = lperm[k + j];
            __half2 gg[16];
#pragma unroll
            for (int j = 0; j < 16; j++)
                gg[j] = *(const __half2*)(xs + (size_t)ss[j] * 8 + p * 2);
            float px = 0.f, py = 0.f;
#pragma unroll
            for (int j = 0; j < 16; j++) {
                float2 f = __half22float2(gg[j]);
                px += f.x; py += f.y;
            }
            acc.x += px; acc.y += py;
        }
        for (; k < lend; ++k) {
            float2 f = __half22float2(*(const __half2*)(xs + (size_t)lperm[k] * 8 + p * 2));
            acc.x += f.x; acc.y += f.y;
        }
    } else {
        __syncthreads();  // match barrier
        for (int k = se.x; k < se.y; ++k) {
            float2 f = __half22float2(*(const __half2*)(xs + (size_t)perm[k] * 8 + p * 2));
            acc.x += f.x; acc.y += f.y;
        }
    }
    if (valid) {
        float2 f = __half22float2(*(const __half2*)(xs + (size_t)node * 8 + p * 2));  // self
        y[nl][2 * p] = acc.x + f.x;
        y[nl][2 * p + 1] = acc.y + f.y;
    }
    __syncthreads();
    if (valid) {
        float dv = dinv[node];
        float yy[IN_DIM];
#pragma unroll
        for (int k2 = 0; k2 < IN_DIM; k2++) yy[k2] = y[nl][k2];
        int c0 = p * 8;
#pragma unroll
        for (int q = 0; q < 8; q++) {
            float z = 0.f;
#pragma unroll
            for (int k2 = 0; k2 < IN_DIM; k2++) z += yy[k2] * w1[k2 * HID_DIM + c0 + q];
            ash[nl][c0 + q] = fmaxf(dv * z + bsh[c0 + q], 0.f);
        }
    }
    __syncthreads();
    if (valid) {
        float dv = dinv[node];
        int c = p * 4;
        float z0 = 0.f, z1 = 0.f, z2 = 0.f, z3 = 0.f;
#pragma unroll
        for (int k2 = 0; k2 < HID_DIM; k2++) {
            float a = ash[nl][k2];
            z0 += a * w2[k2 * LAT_DIM + c];
            z1 += a * w2[k2 * LAT_DIM + c + 1];
            z2 += a * w2[k2 * LAT_DIM + c + 2];
            z3 += a * w2[k2 * LAT_DIM + c + 3];
        }
        __half2 h0 = __floats2half2_rn(dv * z0, dv * z1);
        __half2 h1 = __floats2half2_rn(dv * z2, dv * z3);
        uint2 u;
        u.x = *(unsigned*)&h0;
        u.y = *(unsigned*)&h1;
        *(uint2*)(h2s + (size_t)node * LAT_DIM + c) = u;
    }
}

// ---------------- layer-2: 64 nodes/block, 4 lanes/node x 8B, MLP-16, float4 out ----------------
__global__ void __launch_bounds__(256) k_agg2(const int2* __restrict__ rowse,
                                              const int* __restrict__ perm,
                                              const __half* __restrict__ h2s,
                                              const float* __restrict__ dinv,
                                              const float* __restrict__ b2,
                                              float* __restrict__ out, int N) {
    __shared__ int lperm[LP2_CAP];
    int t = threadIdx.x;
    int n0 = blockIdx.x * 64;
    int node = n0 + (t >> 2), p = t & 3;
    int nlast = min(n0 + 63, N - 1);   // 64-group never crosses a bucket (64 | 128)
    int gbeg = rowse[n0].x;
    int gend = rowse[nlast].y;
    int m = gend - gbeg;
    int2 se = (node <= nlast) ? rowse[node] : make_int2(gbeg, gbeg);
    float4 acc = make_float4(0.f, 0.f, 0.f, 0.f);
    if (m <= LP2_CAP) {
        for (int i = t; i < m; i += 256) lperm[i] = perm[gbeg + i];  // regular: L2/L3 hit
        __syncthreads();
        int k = se.x - gbeg, lend = se.y - gbeg;
        for (; k + 16 <= lend; k += 16) {
            int ss[16];
#pragma unroll
            for (int j = 0; j < 16; j++) ss[j] = lperm[k + j];
            uint2 gg[16];
#pragma unroll
            for (int j = 0; j < 16; j++)
                gg[j] = *(const uint2*)(h2s + (size_t)ss[j] * LAT_DIM + p * 4);
#pragma unroll
            for (int j = 0; j < 16; j++) {
                float2 f0 = __half22float2(*(const __half2*)&gg[j].x);
                float2 f1 = __half22float2(*(const __half2*)&gg[j].y);
                acc.x += f0.x; acc.y += f0.y; acc.z += f1.x; acc.w += f1.y;
            }
        }
        for (; k < lend; ++k) {
            uint2 g = *(const uint2*)(h2s + (size_t)lperm[k] * LAT_DIM + p * 4);
            float2 f0 = __half22float2(*(const __half2*)&g.x);
            float2 f1 = __half22float2(*(const __half2*)&g.y);
            acc.x += f0.x; acc.y += f0.y; acc.z += f1.x; acc.w += f1.y;
        }
    } else {
        __syncthreads();  // match barrier
        for (int k = se.x; k < se.y; ++k) {
            uint2 g = *(const uint2*)(h2s + (size_t)perm[k] * LAT_DIM + p * 4);
            float2 f0 = __half22float2(*(const __half2*)&g.x);
            float2 f1 = __half22float2(*(const __half2*)&g.y);
            acc.x += f0.x; acc.y += f0.y; acc.z += f1.x; acc.w += f1.y;
        }
    }
    if (node < N) {
        uint2 hh = *(const uint2*)(h2s + (size_t)node * LAT_DIM + p * 4);  // self-loop
        float2 h0 = __half22float2(*(const __half2*)&hh.x);
        float2 h1 = __half22float2(*(const __half2*)&hh.y);
        float dv = dinv[node];
        float4 bb = *(const float4*)(b2 + p * 4);
        float4 o;
        o.x = dv * (acc.x + h0.x) + bb.x;
        o.y = dv * (acc.y + h0.y) + bb.y;
        o.z = dv * (acc.z + h1.x) + bb.z;
        o.w = dv * (acc.w + h1.y) + bb.w;
        *(float4*)(out + (size_t)node * LAT_DIM + p * 4) = o;
    }
}

extern "C" void kernel_launch(void* const* d_in, const int* in_sizes, int n_in,
                              void* d_out, int out_size, void* d_ws, size_t ws_size,
                              hipStream_t stream) {
    const float* x  = (const float*)d_in[0];
    const int*   ei = (const int*)d_in[1];
    const float* W1 = (const float*)d_in[2];
    const float* b1 = (const float*)d_in[3];
    const float* W2 = (const float*)d_in[4];
    const float* b2 = (const float*)d_in[5];
    float* out = (float*)d_out;

    const int N = N_NODES, E = N_EDGES;
    const int* src = ei;       // edge_index[0]
    const int* dst = ei + E;   // edge_index[1]

    // workspace carve (256B aligned)
    char* ws = (char*)d_ws;
    size_t off = 0;
    auto take = [&](size_t bytes) -> void* {
        void* p = ws + off;
        off += (bytes + 255) & ~(size_t)255;
        return p;
    };
    int*    bcur  = (int*)take((size_t)NB * 4);
    int*    bedge = (int*)take((size_t)NB * CAP * 4);
    int*    perm  = (int*)take((size_t)NB * CAP * 4);
    int2*   rowse = (int2*)take((size_t)N * 8);
    float*  dinv  = (float*)take((size_t)N * 4);
    __half* xs    = (__half*)take((size_t)N * 8 * 2);
    __half* h2s   = (__half*)take((size_t)N * LAT_DIM * 2);

    const int B = 256;
    k_init<<<(NB + B - 1) / B, B, 0, stream>>>(bcur);
    k_bplace<<<AB_BLOCKS, PL_T, 0, stream>>>(src, dst, bcur, bedge, E);
    k_sort<<<NB, SORT_T, 0, stream>>>(bcur, bedge, x, rowse, perm, dinv, xs, N);
    k_agg1f<<<(N + 63) / 64, B, 0, stream>>>(rowse, perm, xs, dinv, b1, W1, W2, h2s, N);
    k_agg2<<<(N + 63) / 64, B, 0, stream>>>(rowse, perm, h2s, dinv, b2, out, N);
}

// Round 20
// 101.992 us; speedup vs baseline: 1.0657x; 1.0657x over previous
//
#include <hip/hip_runtime.h>
#include <hip/hip_fp16.h>

#define N_NODES 100000
#define N_EDGES 3200000
#define IN_DIM 6
#define HID_DIM 32
#define LAT_DIM 16

#define NPB 128                      // nodes per bucket (dst >> 7)
#define NB 782                       // ceil(100000 / 128)
#define CAP 4800                     // bucket segment capacity (mean 4092, sigma 64)
#define AB_BLOCKS 512
#define CH ((N_EDGES + AB_BLOCKS - 1) / AB_BLOCKS)   // 6250 edges per place block (even)
#define PL_T 512                     // threads in k_bplace
#define SORT_T 512                   // threads in k_sort
#define LP2_CAP 2560                 // 64-node perm stage (mean 2048, sigma 45)

// ---------------- place edges: int2 loads, LDS counting-sort staging -> coalesced writes ----------------
// bcur[] holds RELATIVE per-bucket counts (memset to 0 by host); segment base = b*CAP.
__global__ void __launch_bounds__(PL_T) k_bplace(const int* __restrict__ src,
                                                 const int* __restrict__ dst,
                                                 int* __restrict__ bcur,
                                                 int* __restrict__ bedge, int E) {
    __shared__ int hist[NB];
    __shared__ int lbase[NB];
    __shared__ int gbase[NB];
    __shared__ int cur[NB];
    __shared__ int part[PL_T];
    __shared__ int stage[CH];
    __shared__ unsigned short sbkt[CH];
    int t = threadIdx.x;
    for (int i = t; i < NB; i += PL_T) { hist[i] = 0; cur[i] = 0; }
    __syncthreads();
    int beg = blockIdx.x * CH, end = min(beg + CH, E);
    int nv = (end - beg) >> 1;                       // CH even, beg*4 8B-aligned
    const int2* dst2 = (const int2*)(dst + beg);
    const long long* src2 = (const long long*)(src + beg);  // nt-legal scalar type
    // pass 1: histogram (regular dst loads -- slice re-read in pass 2, L1-hot)
    for (int i = t; i < nv; i += PL_T) {
        int2 d = dst2[i];
        atomicAdd(&hist[d.x >> 7], 1);
        atomicAdd(&hist[d.y >> 7], 1);
    }
    if (((end - beg) & 1) && t == 0) atomicAdd(&hist[dst[end - 1] >> 7], 1);
    __syncthreads();
    // exclusive scan of hist -> lbase (2 elems/thread)
    int i0 = 2 * t;
    int a = (i0 < NB) ? hist[i0] : 0;
    int b = (i0 + 1 < NB) ? hist[i0 + 1] : 0;
    part[t] = a + b;
    __syncthreads();
    for (int off = 1; off < PL_T; off <<= 1) {
        int v = (t >= off) ? part[t - off] : 0;
        __syncthreads();
        part[t] += v;
        __syncthreads();
    }
    int ex = (t == 0) ? 0 : part[t - 1];
    if (i0 < NB) lbase[i0] = ex;
    if (i0 + 1 < NB) lbase[i0 + 1] = ex + a;
    __syncthreads();
    // reserve global ranges per bucket (relative cursor + b*CAP base)
    for (int i = t; i < NB; i += PL_T)
        gbase[i] = hist[i] ? (i * CAP + atomicAdd(&bcur[i], hist[i])) : 0;
    __syncthreads();
    // pass 2: scatter into LDS staging, sorted by bucket (dst L1-hot; src read-once nt)
    for (int i = t; i < nv; i += PL_T) {
        int2 d = dst2[i];
        long long sv = __builtin_nontemporal_load(src2 + i);
        int s0 = (int)(sv & 0xFFFFFFFFLL);
        int s1 = (int)(sv >> 32);
        int bkt0 = d.x >> 7;
        int r0 = atomicAdd(&cur[bkt0], 1);
        int pos0 = lbase[bkt0] + r0;
        stage[pos0] = (s0 << 7) | (d.x & (NPB - 1));
        sbkt[pos0] = (unsigned short)bkt0;
        int bkt1 = d.y >> 7;
        int r1 = atomicAdd(&cur[bkt1], 1);
        int pos1 = lbase[bkt1] + r1;
        stage[pos1] = (s1 << 7) | (d.y & (NPB - 1));
        sbkt[pos1] = (unsigned short)bkt1;
    }
    if (((end - beg) & 1) && t == 0) {
        int d = dst[end - 1], s = src[end - 1];
        int bkt = d >> 7;
        int r = atomicAdd(&cur[bkt], 1);
        int pos = lbase[bkt] + r;
        stage[pos] = (s << 7) | (d & (NPB - 1));
        sbkt[pos] = (unsigned short)bkt;
    }
    __syncthreads();
    // stream out: coalesced within bucket runs; regular store (k_sort re-reads via L2/L3)
    int total = end - beg;
    for (int j = t; j < total; j += PL_T) {
        int bkt = sbkt[j];
        bedge[gbase[bkt] + (j - lbase[bkt])] = stage[j];
    }
}

// ---------------- per-bucket counting sort, SINGLE global pass over bedge ----------------
__global__ void __launch_bounds__(SORT_T) k_sort(const int* __restrict__ bcur,
                                                 const int* __restrict__ bedge,
                                                 const float* __restrict__ x,
                                                 int2* __restrict__ rowse,
                                                 int* __restrict__ perm,
                                                 float* __restrict__ dinv,
                                                 __half* __restrict__ xs, int N) {
    int b = blockIdx.x;
    __shared__ int cnt[NPB], base[NPB], cur[NPB], scn[NPB];
    __shared__ float dvs[NPB];
    __shared__ int raw[CAP];   // 19.2 KB
    __shared__ int srt[CAP];   // 19.2 KB
    int t = threadIdx.x;
    if (t < NPB) cnt[t] = 0;
    __syncthreads();
    int beg = b * CAP;
    int m = bcur[b];           // relative count
    // single global read: stash word + histogram in one pass
    for (int k = t; k < m; k += SORT_T) {
        int w = bedge[beg + k];
        raw[k] = w;
        atomicAdd(&cnt[w & (NPB - 1)], 1);
    }
    __syncthreads();
    if (t < NPB) scn[t] = cnt[t];
    __syncthreads();
    for (int off = 1; off < NPB; off <<= 1) {
        int v = 0;
        if (t < NPB && t >= off) v = scn[t - off];
        __syncthreads();
        if (t < NPB) scn[t] += v;
        __syncthreads();
    }
    if (t < NPB) {
        int ex = scn[t] - cnt[t];  // exclusive
        base[t] = ex;
        cur[t] = 0;
        int node = (b << 7) + t;
        if (node < N) {
            float dv = rsqrtf((float)(cnt[t] + 1));  // +1 self-loop
            dvs[t] = dv;
            dinv[node] = dv;
            rowse[node] = make_int2(beg + ex, beg + ex + cnt[t]);
        }
    }
    __syncthreads();
    // LDS -> LDS scatter (no global traffic)
    for (int k = t; k < m; k += SORT_T) {
        int w = raw[k];
        int dl = w & (NPB - 1);
        int pos = base[dl] + atomicAdd(&cur[dl], 1);
        srt[pos] = w >> 7;
    }
    __syncthreads();
    // coalesced stream-out; regular store (perm read twice downstream)
    for (int k = t; k < m; k += SORT_T)
        perm[beg + k] = srt[k];
    // fused: xs[n][d] = fp16(x[n][d] * dinv[n]), padded to 8 halfs (16B rows)
    for (int i = t; i < NPB * 4; i += SORT_T) {
        int nl = i >> 2, d2 = (i & 3) * 2;
        int node = (b << 7) + nl;
        if (node < N) {
            float dv = dvs[nl];
            float v0 = (d2 < IN_DIM) ? x[(size_t)node * IN_DIM + d2] * dv : 0.f;
            float v1 = (d2 + 1 < IN_DIM) ? x[(size_t)node * IN_DIM + d2 + 1] * dv : 0.f;
            *(__half2*)(xs + (size_t)node * 8 + d2) = __floats2half2_rn(v0, v1);
        }
    }
}

// ---------------- layer 1 fused: 64 nodes/block, 4 lanes/node, half2 MLP-16 gather
//                  -> W1+relu -> W2 -> h2s (fp16) ----------------
__global__ void __launch_bounds__(256) k_agg1f(const int2* __restrict__ rowse,
                                               const int* __restrict__ perm,
                                               const __half* __restrict__ xs,
                                               const float* __restrict__ dinv,
                                               const float* __restrict__ b1,
                                               const float* __restrict__ W1,
                                               const float* __restrict__ W2,
                                               __half* __restrict__ h2s, int N) {
    __shared__ float w1[IN_DIM * HID_DIM];
    __shared__ float w2[HID_DIM * LAT_DIM];
    __shared__ float bsh[HID_DIM];
    __shared__ float ash[64][HID_DIM + 1];
    __shared__ float y[64][9];       // pad 9: avoid 4-way conflict on row reads
    __shared__ int lperm[LP2_CAP];
    int t = threadIdx.x;
    for (int i = t; i < IN_DIM * HID_DIM; i += 256) w1[i] = W1[i];
    for (int i = t; i < HID_DIM * LAT_DIM; i += 256) w2[i] = W2[i];
    if (t < HID_DIM) bsh[t] = b1[t];
    int nl = t >> 2, p = t & 3;
    int n0 = blockIdx.x * 64;
    int node = n0 + nl;
    int nlast = min(n0 + 63, N - 1);   // 64-group never crosses a bucket (64 | 128)
    int gbeg = rowse[n0].x;
    int gend = rowse[nlast].y;
    int m = gend - gbeg;
    bool valid = (node <= nlast);
    int2 se = valid ? rowse[node] : make_int2(gbeg, gbeg);
    float2 acc = make_float2(0.f, 0.f);
    if (m <= LP2_CAP) {
        for (int i = t; i < m; i += 256) lperm[i] = perm[gbeg + i];  // regular: L2/L3 hit
        __syncthreads();
        int k = se.x - gbeg, lend = se.y - gbeg;
        for (; k + 16 <= lend; k += 16) {
            int ss[16];
#pragma unroll
            for (int j = 0; j < 16; j++) ss[j] = lperm[k + j];
            __half2 gg[16];
#pragma unroll
            for (int j = 0; j < 16; j++)
                gg[j] = *(const __half2*)(xs + (size_t)ss[j] * 8 + p * 2);
            float px = 0.f, py = 0.f;
#pragma unroll
            for (int j = 0; j < 16; j++) {
                float2 f = __half22float2(gg[j]);
                px += f.x; py += f.y;
            }
            acc.x += px; acc.y += py;
        }
        for (; k < lend; ++k) {
            float2 f = __half22float2(*(const __half2*)(xs + (size_t)lperm[k] * 8 + p * 2));
            acc.x += f.x; acc.y += f.y;
        }
    } else {
        __syncthreads();  // match barrier
        for (int k = se.x; k < se.y; ++k) {
            float2 f = __half22float2(*(const __half2*)(xs + (size_t)perm[k] * 8 + p * 2));
            acc.x += f.x; acc.y += f.y;
        }
    }
    if (valid) {
        float2 f = __half22float2(*(const __half2*)(xs + (size_t)node * 8 + p * 2));  // self
        y[nl][2 * p] = acc.x + f.x;
        y[nl][2 * p + 1] = acc.y + f.y;
    }
    __syncthreads();
    if (valid) {
        float dv = dinv[node];
        float yy[IN_DIM];
#pragma unroll
        for (int k2 = 0; k2 < IN_DIM; k2++) yy[k2] = y[nl][k2];
        int c0 = p * 8;
#pragma unroll
        for (int q = 0; q < 8; q++) {
            float z = 0.f;
#pragma unroll
            for (int k2 = 0; k2 < IN_DIM; k2++) z += yy[k2] * w1[k2 * HID_DIM + c0 + q];
            ash[nl][c0 + q] = fmaxf(dv * z + bsh[c0 + q], 0.f);
        }
    }
    __syncthreads();
    if (valid) {
        float dv = dinv[node];
        int c = p * 4;
        float z0 = 0.f, z1 = 0.f, z2 = 0.f, z3 = 0.f;
#pragma unroll
        for (int k2 = 0; k2 < HID_DIM; k2++) {
            float a = ash[nl][k2];
            z0 += a * w2[k2 * LAT_DIM + c];
            z1 += a * w2[k2 * LAT_DIM + c + 1];
            z2 += a * w2[k2 * LAT_DIM + c + 2];
            z3 += a * w2[k2 * LAT_DIM + c + 3];
        }
        __half2 h0 = __floats2half2_rn(dv * z0, dv * z1);
        __half2 h1 = __floats2half2_rn(dv * z2, dv * z3);
        uint2 u;
        u.x = *(unsigned*)&h0;
        u.y = *(unsigned*)&h1;
        *(uint2*)(h2s + (size_t)node * LAT_DIM + c) = u;
    }
}

// ---------------- layer-2: 64 nodes/block, 4 lanes/node x 8B, MLP-16, float4 out ----------------
__global__ void __launch_bounds__(256) k_agg2(const int2* __restrict__ rowse,
                                              const int* __restrict__ perm,
                                              const __half* __restrict__ h2s,
                                              const float* __restrict__ dinv,
                                              const float* __restrict__ b2,
                                              float* __restrict__ out, int N) {
    __shared__ int lperm[LP2_CAP];
    int t = threadIdx.x;
    int n0 = blockIdx.x * 64;
    int node = n0 + (t >> 2), p = t & 3;
    int nlast = min(n0 + 63, N - 1);   // 64-group never crosses a bucket (64 | 128)
    int gbeg = rowse[n0].x;
    int gend = rowse[nlast].y;
    int m = gend - gbeg;
    int2 se = (node <= nlast) ? rowse[node] : make_int2(gbeg, gbeg);
    float4 acc = make_float4(0.f, 0.f, 0.f, 0.f);
    if (m <= LP2_CAP) {
        for (int i = t; i < m; i += 256) lperm[i] = perm[gbeg + i];  // regular: L2/L3 hit
        __syncthreads();
        int k = se.x - gbeg, lend = se.y - gbeg;
        for (; k + 16 <= lend; k += 16) {
            int ss[16];
#pragma unroll
            for (int j = 0; j < 16; j++) ss[j] = lperm[k + j];
            uint2 gg[16];
#pragma unroll
            for (int j = 0; j < 16; j++)
                gg[j] = *(const uint2*)(h2s + (size_t)ss[j] * LAT_DIM + p * 4);
#pragma unroll
            for (int j = 0; j < 16; j++) {
                float2 f0 = __half22float2(*(const __half2*)&gg[j].x);
                float2 f1 = __half22float2(*(const __half2*)&gg[j].y);
                acc.x += f0.x; acc.y += f0.y; acc.z += f1.x; acc.w += f1.y;
            }
        }
        for (; k < lend; ++k) {
            uint2 g = *(const uint2*)(h2s + (size_t)lperm[k] * LAT_DIM + p * 4);
            float2 f0 = __half22float2(*(const __half2*)&g.x);
            float2 f1 = __half22float2(*(const __half2*)&g.y);
            acc.x += f0.x; acc.y += f0.y; acc.z += f1.x; acc.w += f1.y;
        }
    } else {
        __syncthreads();  // match barrier
        for (int k = se.x; k < se.y; ++k) {
            uint2 g = *(const uint2*)(h2s + (size_t)perm[k] * LAT_DIM + p * 4);
            float2 f0 = __half22float2(*(const __half2*)&g.x);
            float2 f1 = __half22float2(*(const __half2*)&g.y);
            acc.x += f0.x; acc.y += f0.y; acc.z += f1.x; acc.w += f1.y;
        }
    }
    if (node < N) {
        uint2 hh = *(const uint2*)(h2s + (size_t)node * LAT_DIM + p * 4);  // self-loop
        float2 h0 = __half22float2(*(const __half2*)&hh.x);
        float2 h1 = __half22float2(*(const __half2*)&hh.y);
        float dv = dinv[node];
        float4 bb = *(const float4*)(b2 + p * 4);
        float4 o;
        o.x = dv * (acc.x + h0.x) + bb.x;
        o.y = dv * (acc.y + h0.y) + bb.y;
        o.z = dv * (acc.z + h1.x) + bb.z;
        o.w = dv * (acc.w + h1.y) + bb.w;
        *(float4*)(out + (size_t)node * LAT_DIM + p * 4) = o;
    }
}

extern "C" void kernel_launch(void* const* d_in, const int* in_sizes, int n_in,
                              void* d_out, int out_size, void* d_ws, size_t ws_size,
                              hipStream_t stream) {
    const float* x  = (const float*)d_in[0];
    const int*   ei = (const int*)d_in[1];
    const float* W1 = (const float*)d_in[2];
    const float* b1 = (const float*)d_in[3];
    const float* W2 = (const float*)d_in[4];
    const float* b2 = (const float*)d_in[5];
    float* out = (float*)d_out;

    const int N = N_NODES, E = N_EDGES;
    const int* src = ei;       // edge_index[0]
    const int* dst = ei + E;   // edge_index[1]

    // workspace carve (256B aligned)
    char* ws = (char*)d_ws;
    size_t off = 0;
    auto take = [&](size_t bytes) -> void* {
        void* p = ws + off;
        off += (bytes + 255) & ~(size_t)255;
        return p;
    };
    int*    bcur  = (int*)take((size_t)NB * 4);
    int*    bedge = (int*)take((size_t)NB * CAP * 4);
    int*    perm  = (int*)take((size_t)NB * CAP * 4);
    int2*   rowse = (int2*)take((size_t)N * 8);
    float*  dinv  = (float*)take((size_t)N * 4);
    __half* xs    = (__half*)take((size_t)N * 8 * 2);
    __half* h2s   = (__half*)take((size_t)N * LAT_DIM * 2);

    hipMemsetAsync(bcur, 0, (size_t)NB * 4, stream);  // relative cursors

    const int B = 256;
    k_bplace<<<AB_BLOCKS, PL_T, 0, stream>>>(src, dst, bcur, bedge, E);
    k_sort<<<NB, SORT_T, 0, stream>>>(bcur, bedge, x, rowse, perm, dinv, xs, N);
    k_agg1f<<<(N + 63) / 64, B, 0, stream>>>(rowse, perm, xs, dinv, b1, W1, W2, h2s, N);
    k_agg2<<<(N + 63) / 64, B, 0, stream>>>(rowse, perm, h2s, dinv, b2, out, N);
}

// Round 21
// 99.059 us; speedup vs baseline: 1.0972x; 1.0296x over previous
//
#include <hip/hip_runtime.h>
#include <hip/hip_fp16.h>

#define N_NODES 100000
#define N_EDGES 3200000
#define IN_DIM 6
#define HID_DIM 32
#define LAT_DIM 16

#define NPB 128                      // nodes per bucket (dst >> 7)
#define NB 782                       // ceil(100000 / 128)
#define CAP 4800                     // bucket segment capacity (mean 4092, sigma 64); CAP*4 % 16 == 0
#define AB_BLOCKS 512
#define CH ((N_EDGES + AB_BLOCKS - 1) / AB_BLOCKS)   // 6250 edges per place block (even)
#define PL_T 512                     // threads in k_bplace
#define SORT_T 512                   // threads in k_sort
#define LP2_CAP 2560                 // 64-node perm stage (mean 2048+slack; >= mm+3 max ~2300)

// ---------------- place edges: int2 loads, LDS counting-sort staging -> coalesced writes ----------------
// bcur[] holds RELATIVE per-bucket counts (memset to 0 by host); segment base = b*CAP.
__global__ void __launch_bounds__(PL_T) k_bplace(const int* __restrict__ src,
                                                 const int* __restrict__ dst,
                                                 int* __restrict__ bcur,
                                                 int* __restrict__ bedge, int E) {
    __shared__ int hist[NB];
    __shared__ int lbase[NB];
    __shared__ int gbase[NB];
    __shared__ int cur[NB];
    __shared__ int part[PL_T];
    __shared__ int stage[CH];
    __shared__ unsigned short sbkt[CH];
    int t = threadIdx.x;
    for (int i = t; i < NB; i += PL_T) { hist[i] = 0; cur[i] = 0; }
    __syncthreads();
    int beg = blockIdx.x * CH, end = min(beg + CH, E);
    int nv = (end - beg) >> 1;                       // CH even, beg*4 8B-aligned
    const int2* dst2 = (const int2*)(dst + beg);
    const long long* src2 = (const long long*)(src + beg);  // nt-legal scalar type
    // pass 1: histogram (regular dst loads -- slice re-read in pass 2, L1-hot)
    for (int i = t; i < nv; i += PL_T) {
        int2 d = dst2[i];
        atomicAdd(&hist[d.x >> 7], 1);
        atomicAdd(&hist[d.y >> 7], 1);
    }
    if (((end - beg) & 1) && t == 0) atomicAdd(&hist[dst[end - 1] >> 7], 1);
    __syncthreads();
    // exclusive scan of hist -> lbase (2 elems/thread)
    int i0 = 2 * t;
    int a = (i0 < NB) ? hist[i0] : 0;
    int b = (i0 + 1 < NB) ? hist[i0 + 1] : 0;
    part[t] = a + b;
    __syncthreads();
    for (int off = 1; off < PL_T; off <<= 1) {
        int v = (t >= off) ? part[t - off] : 0;
        __syncthreads();
        part[t] += v;
        __syncthreads();
    }
    int ex = (t == 0) ? 0 : part[t - 1];
    if (i0 < NB) lbase[i0] = ex;
    if (i0 + 1 < NB) lbase[i0 + 1] = ex + a;
    __syncthreads();
    // reserve global ranges per bucket (relative cursor + b*CAP base)
    for (int i = t; i < NB; i += PL_T)
        gbase[i] = hist[i] ? (i * CAP + atomicAdd(&bcur[i], hist[i])) : 0;
    __syncthreads();
    // pass 2: scatter into LDS staging, sorted by bucket (dst L1-hot; src read-once nt)
    for (int i = t; i < nv; i += PL_T) {
        int2 d = dst2[i];
        long long sv = __builtin_nontemporal_load(src2 + i);
        int s0 = (int)(sv & 0xFFFFFFFFLL);
        int s1 = (int)(sv >> 32);
        int bkt0 = d.x >> 7;
        int r0 = atomicAdd(&cur[bkt0], 1);
        int pos0 = lbase[bkt0] + r0;
        stage[pos0] = (s0 << 7) | (d.x & (NPB - 1));
        sbkt[pos0] = (unsigned short)bkt0;
        int bkt1 = d.y >> 7;
        int r1 = atomicAdd(&cur[bkt1], 1);
        int pos1 = lbase[bkt1] + r1;
        stage[pos1] = (s1 << 7) | (d.y & (NPB - 1));
        sbkt[pos1] = (unsigned short)bkt1;
    }
    if (((end - beg) & 1) && t == 0) {
        int d = dst[end - 1], s = src[end - 1];
        int bkt = d >> 7;
        int r = atomicAdd(&cur[bkt], 1);
        int pos = lbase[bkt] + r;
        stage[pos] = (s << 7) | (d & (NPB - 1));
        sbkt[pos] = (unsigned short)bkt;
    }
    __syncthreads();
    // stream out: coalesced within bucket runs; regular store (k_sort re-reads via L2/L3)
    int total = end - beg;
    for (int j = t; j < total; j += PL_T) {
        int bkt = sbkt[j];
        bedge[gbase[bkt] + (j - lbase[bkt])] = stage[j];
    }
}

// ---------------- per-bucket counting sort, SINGLE global pass over bedge (int4 copies) ----------------
__global__ void __launch_bounds__(SORT_T) k_sort(const int* __restrict__ bcur,
                                                 const int* __restrict__ bedge,
                                                 const float* __restrict__ x,
                                                 int2* __restrict__ rowse,
                                                 int* __restrict__ perm,
                                                 float* __restrict__ dinv,
                                                 __half* __restrict__ xs, int N) {
    int b = blockIdx.x;
    __shared__ int cnt[NPB], base[NPB], cur[NPB], scn[NPB];
    __shared__ float dvs[NPB];
    __shared__ __align__(16) int raw[CAP];   // 19.2 KB
    __shared__ __align__(16) int srt[CAP];   // 19.2 KB
    int t = threadIdx.x;
    if (t < NPB) cnt[t] = 0;
    __syncthreads();
    int beg = b * CAP;         // 16B-aligned (CAP*4 % 16 == 0)
    int m = bcur[b];           // relative count
    int mv = m >> 2, tail = mv << 2;
    // single global read (int4): stash word + histogram in one pass
    const int4* bedge4 = (const int4*)(bedge + beg);
    for (int k4 = t; k4 < mv; k4 += SORT_T) {
        int4 w4 = bedge4[k4];
        ((int4*)raw)[k4] = w4;
        atomicAdd(&cnt[w4.x & (NPB - 1)], 1);
        atomicAdd(&cnt[w4.y & (NPB - 1)], 1);
        atomicAdd(&cnt[w4.z & (NPB - 1)], 1);
        atomicAdd(&cnt[w4.w & (NPB - 1)], 1);
    }
    if (t < (m - tail)) {      // scalar tail (<=3)
        int w = bedge[beg + tail + t];
        raw[tail + t] = w;
        atomicAdd(&cnt[w & (NPB - 1)], 1);
    }
    __syncthreads();
    if (t < NPB) scn[t] = cnt[t];
    __syncthreads();
    for (int off = 1; off < NPB; off <<= 1) {
        int v = 0;
        if (t < NPB && t >= off) v = scn[t - off];
        __syncthreads();
        if (t < NPB) scn[t] += v;
        __syncthreads();
    }
    if (t < NPB) {
        int ex = scn[t] - cnt[t];  // exclusive
        base[t] = ex;
        cur[t] = 0;
        int node = (b << 7) + t;
        if (node < N) {
            float dv = rsqrtf((float)(cnt[t] + 1));  // +1 self-loop
            dvs[t] = dv;
            dinv[node] = dv;
            rowse[node] = make_int2(beg + ex, beg + ex + cnt[t]);
        }
    }
    __syncthreads();
    // LDS -> LDS scatter (no global traffic)
    for (int k = t; k < m; k += SORT_T) {
        int w = raw[k];
        int dl = w & (NPB - 1);
        int pos = base[dl] + atomicAdd(&cur[dl], 1);
        srt[pos] = w >> 7;
    }
    __syncthreads();
    // coalesced int4 stream-out; regular store (perm read twice downstream)
    for (int k4 = t; k4 < mv; k4 += SORT_T)
        ((int4*)(perm + beg))[k4] = ((const int4*)srt)[k4];
    if (t < (m - tail))
        perm[beg + tail + t] = srt[tail + t];
    // fused: xs[n][d] = fp16(x[n][d] * dinv[n]), padded to 8 halfs (16B rows)
    for (int i = t; i < NPB * 4; i += SORT_T) {
        int nl = i >> 2, d2 = (i & 3) * 2;
        int node = (b << 7) + nl;
        if (node < N) {
            float dv = dvs[nl];
            float v0 = (d2 < IN_DIM) ? x[(size_t)node * IN_DIM + d2] * dv : 0.f;
            float v1 = (d2 + 1 < IN_DIM) ? x[(size_t)node * IN_DIM + d2 + 1] * dv : 0.f;
            *(__half2*)(xs + (size_t)node * 8 + d2) = __floats2half2_rn(v0, v1);
        }
    }
}

// ---------------- layer 1 fused: 64 nodes/block, 4 lanes/node, half2 MLP-16 gather
//                  (int4 lperm staging) -> W1+relu -> W2 -> h2s (fp16) ----------------
__global__ void __launch_bounds__(256) k_agg1f(const int2* __restrict__ rowse,
                                               const int* __restrict__ perm,
                                               const __half* __restrict__ xs,
                                               const float* __restrict__ dinv,
                                               const float* __restrict__ b1,
                                               const float* __restrict__ W1,
                                               const float* __restrict__ W2,
                                               __half* __restrict__ h2s, int N) {
    __shared__ float w1[IN_DIM * HID_DIM];
    __shared__ float w2[HID_DIM * LAT_DIM];
    __shared__ float bsh[HID_DIM];
    __shared__ float ash[64][HID_DIM + 1];
    __shared__ float y[64][9];       // pad 9: avoid 4-way conflict on row reads
    __shared__ __align__(16) int lperm[LP2_CAP];
    int t = threadIdx.x;
    for (int i = t; i < IN_DIM * HID_DIM; i += 256) w1[i] = W1[i];
    for (int i = t; i < HID_DIM * LAT_DIM; i += 256) w2[i] = W2[i];
    if (t < HID_DIM) bsh[t] = b1[t];
    int nl = t >> 2, p = t & 3;
    int n0 = blockIdx.x * 64;
    int node = n0 + nl;
    int nlast = min(n0 + 63, N - 1);   // 64-group never crosses a bucket (64 | 128)
    int gbeg = rowse[n0].x;
    int gend = rowse[nlast].y;
    int abeg = gbeg & ~3;              // 16B-aligned staging base
    int mm = gend - abeg;              // staged count incl. prefix slack (<=3)
    bool valid = (node <= nlast);
    int2 se = valid ? rowse[node] : make_int2(gbeg, gbeg);
    float2 acc = make_float2(0.f, 0.f);
    if (mm + 3 <= LP2_CAP) {
        int mv4 = (mm + 3) >> 2;       // over-stage <=3 ints (never consumed)
        const int4* p4 = (const int4*)(perm + abeg);
        for (int i = t; i < mv4; i += 256) ((int4*)lperm)[i] = p4[i];
        __syncthreads();
        int k = se.x - abeg, lend = se.y - abeg;
        for (; k + 16 <= lend; k += 16) {
            int ss[16];
#pragma unroll
            for (int j = 0; j < 16; j++) ss[j] = lperm[k + j];
            __half2 gg[16];
#pragma unroll
            for (int j = 0; j < 16; j++)
                gg[j] = *(const __half2*)(xs + (size_t)ss[j] * 8 + p * 2);
            float px = 0.f, py = 0.f;
#pragma unroll
            for (int j = 0; j < 16; j++) {
                float2 f = __half22float2(gg[j]);
                px += f.x; py += f.y;
            }
            acc.x += px; acc.y += py;
        }
        for (; k < lend; ++k) {
            float2 f = __half22float2(*(const __half2*)(xs + (size_t)lperm[k] * 8 + p * 2));
            acc.x += f.x; acc.y += f.y;
        }
    } else {
        __syncthreads();  // match barrier
        for (int k = se.x; k < se.y; ++k) {
            float2 f = __half22float2(*(const __half2*)(xs + (size_t)perm[k] * 8 + p * 2));
            acc.x += f.x; acc.y += f.y;
        }
    }
    if (valid) {
        float2 f = __half22float2(*(const __half2*)(xs + (size_t)node * 8 + p * 2));  // self
        y[nl][2 * p] = acc.x + f.x;
        y[nl][2 * p + 1] = acc.y + f.y;
    }
    __syncthreads();
    if (valid) {
        float dv = dinv[node];
        float yy[IN_DIM];
#pragma unroll
        for (int k2 = 0; k2 < IN_DIM; k2++) yy[k2] = y[nl][k2];
        int c0 = p * 8;
#pragma unroll
        for (int q = 0; q < 8; q++) {
            float z = 0.f;
#pragma unroll
            for (int k2 = 0; k2 < IN_DIM; k2++) z += yy[k2] * w1[k2 * HID_DIM + c0 + q];
            ash[nl][c0 + q] = fmaxf(dv * z + bsh[c0 + q], 0.f);
        }
    }
    __syncthreads();
    if (valid) {
        float dv = dinv[node];
        int c = p * 4;
        float z0 = 0.f, z1 = 0.f, z2 = 0.f, z3 = 0.f;
#pragma unroll
        for (int k2 = 0; k2 < HID_DIM; k2++) {
            float a = ash[nl][k2];
            z0 += a * w2[k2 * LAT_DIM + c];
            z1 += a * w2[k2 * LAT_DIM + c + 1];
            z2 += a * w2[k2 * LAT_DIM + c + 2];
            z3 += a * w2[k2 * LAT_DIM + c + 3];
        }
        __half2 h0 = __floats2half2_rn(dv * z0, dv * z1);
        __half2 h1 = __floats2half2_rn(dv * z2, dv * z3);
        uint2 u;
        u.x = *(unsigned*)&h0;
        u.y = *(unsigned*)&h1;
        *(uint2*)(h2s + (size_t)node * LAT_DIM + c) = u;
    }
}

// ---------------- layer-2: 64 nodes/block, 4 lanes/node x 8B, MLP-16, int4 staging, float4 out ----------------
__global__ void __launch_bounds__(256) k_agg2(const int2* __restrict__ rowse,
                                              const int* __restrict__ perm,
                                              const __half* __restrict__ h2s,
                                              const float* __restrict__ dinv,
                                              const float* __restrict__ b2,
                                              float* __restrict__ out, int N) {
    __shared__ __align__(16) int lperm[LP2_CAP];
    int t = threadIdx.x;
    int n0 = blockIdx.x * 64;
    int node = n0 + (t >> 2), p = t & 3;
    int nlast = min(n0 + 63, N - 1);   // 64-group never crosses a bucket (64 | 128)
    int gbeg = rowse[n0].x;
    int gend = rowse[nlast].y;
    int abeg = gbeg & ~3;
    int mm = gend - abeg;
    int2 se = (node <= nlast) ? rowse[node] : make_int2(gbeg, gbeg);
    float4 acc = make_float4(0.f, 0.f, 0.f, 0.f);
    if (mm + 3 <= LP2_CAP) {
        int mv4 = (mm + 3) >> 2;
        const int4* p4 = (const int4*)(perm + abeg);
        for (int i = t; i < mv4; i += 256) ((int4*)lperm)[i] = p4[i];
        __syncthreads();
        int k = se.x - abeg, lend = se.y - abeg;
        for (; k + 16 <= lend; k += 16) {
            int ss[16];
#pragma unroll
            for (int j = 0; j < 16; j++) ss[j] = lperm[k + j];
            uint2 gg[16];
#pragma unroll
            for (int j = 0; j < 16; j++)
                gg[j] = *(const uint2*)(h2s + (size_t)ss[j] * LAT_DIM + p * 4);
#pragma unroll
            for (int j = 0; j < 16; j++) {
                float2 f0 = __half22float2(*(const __half2*)&gg[j].x);
                float2 f1 = __half22float2(*(const __half2*)&gg[j].y);
                acc.x += f0.x; acc.y += f0.y; acc.z += f1.x; acc.w += f1.y;
            }
        }
        for (; k < lend; ++k) {
            uint2 g = *(const uint2*)(h2s + (size_t)lperm[k] * LAT_DIM + p * 4);
            float2 f0 = __half22float2(*(const __half2*)&g.x);
            float2 f1 = __half22float2(*(const __half2*)&g.y);
            acc.x += f0.x; acc.y += f0.y; acc.z += f1.x; acc.w += f1.y;
        }
    } else {
        __syncthreads();  // match barrier
        for (int k = se.x; k < se.y; ++k) {
            uint2 g = *(const uint2*)(h2s + (size_t)perm[k] * LAT_DIM + p * 4);
            float2 f0 = __half22float2(*(const __half2*)&g.x);
            float2 f1 = __half22float2(*(const __half2*)&g.y);
            acc.x += f0.x; acc.y += f0.y; acc.z += f1.x; acc.w += f1.y;
        }
    }
    if (node < N) {
        uint2 hh = *(const uint2*)(h2s + (size_t)node * LAT_DIM + p * 4);  // self-loop
        float2 h0 = __half22float2(*(const __half2*)&hh.x);
        float2 h1 = __half22float2(*(const __half2*)&hh.y);
        float dv = dinv[node];
        float4 bb = *(const float4*)(b2 + p * 4);
        float4 o;
        o.x = dv * (acc.x + h0.x) + bb.x;
        o.y = dv * (acc.y + h0.y) + bb.y;
        o.z = dv * (acc.z + h1.x) + bb.z;
        o.w = dv * (acc.w + h1.y) + bb.w;
        *(float4*)(out + (size_t)node * LAT_DIM + p * 4) = o;
    }
}

extern "C" void kernel_launch(void* const* d_in, const int* in_sizes, int n_in,
                              void* d_out, int out_size, void* d_ws, size_t ws_size,
                              hipStream_t stream) {
    const float* x  = (const float*)d_in[0];
    const int*   ei = (const int*)d_in[1];
    const float* W1 = (const float*)d_in[2];
    const float* b1 = (const float*)d_in[3];
    const float* W2 = (const float*)d_in[4];
    const float* b2 = (const float*)d_in[5];
    float* out = (float*)d_out;

    const int N = N_NODES, E = N_EDGES;
    const int* src = ei;       // edge_index[0]
    const int* dst = ei + E;   // edge_index[1]

    // workspace carve (256B aligned)
    char* ws = (char*)d_ws;
    size_t off = 0;
    auto take = [&](size_t bytes) -> void* {
        void* p = ws + off;
        off += (bytes + 255) & ~(size_t)255;
        return p;
    };
    int*    bcur  = (int*)take((size_t)NB * 4);
    int*    bedge = (int*)take((size_t)NB * CAP * 4);
    int*    perm  = (int*)take((size_t)NB * CAP * 4);
    int2*   rowse = (int2*)take((size_t)N * 8);
    float*  dinv  = (float*)take((size_t)N * 4);
    __half* xs    = (__half*)take((size_t)N * 8 * 2);
    __half* h2s   = (__half*)take((size_t)N * LAT_DIM * 2);

    hipMemsetAsync(bcur, 0, (size_t)NB * 4, stream);  // relative cursors

    const int B = 256;
    k_bplace<<<AB_BLOCKS, PL_T, 0, stream>>>(src, dst, bcur, bedge, E);
    k_sort<<<NB, SORT_T, 0, stream>>>(bcur, bedge, x, rowse, perm, dinv, xs, N);
    k_agg1f<<<(N + 63) / 64, B, 0, stream>>>(rowse, perm, xs, dinv, b1, W1, W2, h2s, N);
    k_agg2<<<(N + 63) / 64, B, 0, stream>>>(rowse, perm, h2s, dinv, b2, out, N);
}